// Round 3
// baseline (5568.840 us; speedup 1.0000x reference)
//
#include <hip/hip_runtime.h>

typedef unsigned short u16;

#define B_   16
#define L_   495
#define D_   384
#define DI_  768
#define DS_  16
#define DTR_ 24

__device__ __forceinline__ float bf2f(u16 u) {
    return __uint_as_float(((unsigned)u) << 16);
}
__device__ __forceinline__ u16 f2bf(float f) {
    unsigned u = __float_as_uint(f);
    unsigned r = 0x7fffu + ((u >> 16) & 1u);
    return (u16)((u + r) >> 16);
}
__device__ __forceinline__ float silu_f(float x) {
    return x / (1.f + __expf(-x));
}
__device__ __forceinline__ float softplus_f(float x) {
    if (x > 15.f) return x;
    return log1pf(__expf(x));
}

// ---- dtype detector: A_log values are in [0, 2.78]. If the raw buffer is
// bf16, ALL u16s decode in-range; if it is f32, the mantissa halves decode
// to random exponents and fail. flag=1 -> bf16, flag=0 -> f32.
__global__ __launch_bounds__(256) void detect_kernel(
    const u16* __restrict__ alog_raw, int* __restrict__ flag)
{
    __shared__ int s_bad;
    if (threadIdx.x == 0) s_bad = 0;
    __syncthreads();
    int bad = 0;
    for (int i = threadIdx.x; i < 98304; i += 256) {
        float v = bf2f(alog_raw[i]);
        if (!(v >= -1e-3f && v <= 2.8f)) bad = 1;   // NaN also lands here
    }
    if (bad) atomicAdd(&s_bad, 1);
    __syncthreads();
    if (threadIdx.x == 0) *flag = (s_bad == 0) ? 1 : 0;
}

// ---- convert raw tensor (bf16 or f32 per flag) to canonical f32
__global__ __launch_bounds__(256) void cvt_kernel(
    const void* __restrict__ src, float* __restrict__ dst, int n,
    const int* __restrict__ flag)
{
    int i = blockIdx.x * 256 + threadIdx.x;
    if (i >= n) return;
    if (*flag) dst[i] = bf2f(((const u16*)src)[i]);
    else       dst[i] = ((const float*)src)[i];
}

// hidden[b,l,c] = concat(cjv[:247], cls, cjv[247:]) + pos_embed
__global__ __launch_bounds__(256) void build_hidden_kernel(
    const float* __restrict__ cjv, const float* __restrict__ cls,
    const float* __restrict__ pos, float* __restrict__ hidden)
{
    int i = blockIdx.x * 256 + threadIdx.x;
    int c = i % D_;
    int l = (i / D_) % L_;
    int b = i / (D_ * L_);
    float v;
    if (l < 247)       v = cjv[((size_t)b * 494 + l) * D_ + c];
    else if (l == 247) v = cls[c];
    else               v = cjv[((size_t)b * 494 + (l - 1)) * D_ + c];
    hidden[i] = v + pos[(size_t)l * D_ + c];
}

// resid = hidden (+ resid); hidden <- rmsnorm(resid)*w   (in-place norm)
__global__ __launch_bounds__(128) void resnorm_kernel(
    float* __restrict__ hidden, float* __restrict__ resid,
    const float* __restrict__ w, int first)
{
    int m = blockIdx.x, tid = threadIdx.x;
    size_t base = (size_t)m * D_;
    float v[3]; float ss = 0.f;
#pragma unroll
    for (int i = 0; i < 3; ++i) {
        int c = tid + i * 128;
        float r = hidden[base + c];
        if (!first) r += resid[base + c];
        resid[base + c] = r;
        v[i] = r; ss += r * r;
    }
    ss += __shfl_xor(ss, 32); ss += __shfl_xor(ss, 16); ss += __shfl_xor(ss, 8);
    ss += __shfl_xor(ss, 4);  ss += __shfl_xor(ss, 2);  ss += __shfl_xor(ss, 1);
    __shared__ float sred[2];
    if ((tid & 63) == 0) sred[tid >> 6] = ss;
    __syncthreads();
    float scale = rsqrtf((sred[0] + sred[1]) * (1.f / D_) + 1e-5f);
#pragma unroll
    for (int i = 0; i < 3; ++i) {
        int c = tid + i * 128;
        hidden[base + c] = v[i] * scale * w[c];
    }
}

// C(M,N) = alpha * A(M,K) @ W(N,K)^T   (A f32 or bf16; W f32; C f32 or bf16)
#define BM 64
#define BN 64
#define BKg 16
template<int AF32, int CF32>
__global__ __launch_bounds__(256) void gemm_aw_t(
    const void* __restrict__ Av, const float* __restrict__ W, void* __restrict__ Cv,
    int M, int N, int K, int ldc, float alpha)
{
    __shared__ float As[BKg][BM + 1];
    __shared__ float Ws[BKg][BN + 1];
    int m0 = blockIdx.x * BM, n0 = blockIdx.y * BN;
    int tid = threadIdx.x;
    int ty = tid >> 4, tx = tid & 15;
    int lr = tid >> 2, lk = (tid & 3) << 2;
    float acc[4][4] = {};
    for (int k0 = 0; k0 < K; k0 += BKg) {
        int am = m0 + lr;
        float a0 = 0.f, a1 = 0.f, a2 = 0.f, a3 = 0.f;
        if (am < M) {
            if (AF32) {
                float4 av = *reinterpret_cast<const float4*>(
                    (const float*)Av + (size_t)am * K + k0 + lk);
                a0 = av.x; a1 = av.y; a2 = av.z; a3 = av.w;
            } else {
                ushort4 av = *reinterpret_cast<const ushort4*>(
                    (const u16*)Av + (size_t)am * K + k0 + lk);
                a0 = bf2f(av.x); a1 = bf2f(av.y); a2 = bf2f(av.z); a3 = bf2f(av.w);
            }
        }
        As[lk][lr] = a0; As[lk + 1][lr] = a1; As[lk + 2][lr] = a2; As[lk + 3][lr] = a3;
        float4 wv = *reinterpret_cast<const float4*>(W + (size_t)(n0 + lr) * K + k0 + lk);
        Ws[lk][lr] = wv.x; Ws[lk + 1][lr] = wv.y;
        Ws[lk + 2][lr] = wv.z; Ws[lk + 3][lr] = wv.w;
        __syncthreads();
#pragma unroll
        for (int kk = 0; kk < BKg; ++kk) {
            float b0 = As[kk][ty * 4], b1 = As[kk][ty * 4 + 1];
            float b2 = As[kk][ty * 4 + 2], b3 = As[kk][ty * 4 + 3];
            float c0 = Ws[kk][tx * 4], c1 = Ws[kk][tx * 4 + 1];
            float c2 = Ws[kk][tx * 4 + 2], c3 = Ws[kk][tx * 4 + 3];
            acc[0][0] += b0 * c0; acc[0][1] += b0 * c1; acc[0][2] += b0 * c2; acc[0][3] += b0 * c3;
            acc[1][0] += b1 * c0; acc[1][1] += b1 * c1; acc[1][2] += b1 * c2; acc[1][3] += b1 * c3;
            acc[2][0] += b2 * c0; acc[2][1] += b2 * c1; acc[2][2] += b2 * c2; acc[2][3] += b2 * c3;
            acc[3][0] += b3 * c0; acc[3][1] += b3 * c1; acc[3][2] += b3 * c2; acc[3][3] += b3 * c3;
        }
        __syncthreads();
    }
#pragma unroll
    for (int i = 0; i < 4; ++i) {
        int m = m0 + ty * 4 + i;
        if (m >= M) continue;
#pragma unroll
        for (int j = 0; j < 4; ++j) {
            float val = alpha * acc[i][j];
            if (CF32) ((float*)Cv)[(size_t)m * ldc + n0 + tx * 4 + j] = val;
            else      ((u16*)Cv)[(size_t)m * ldc + n0 + tx * 4 + j] = f2bf(val);
        }
    }
}

// causal depthwise conv (K=4) + bias + silu, in scan order; xin = xz[:, :768]
__global__ __launch_bounds__(256) void conv_silu_kernel(
    const u16* __restrict__ xz, const float* __restrict__ cw,
    const float* __restrict__ cb, u16* __restrict__ xc, int rev)
{
    int i = blockIdx.x * 256 + threadIdx.x;
    int d = i % DI_;
    int s = (i / DI_) % L_;
    int b = i / (DI_ * L_);
    float acc = cb[d];
#pragma unroll
    for (int k = 0; k < 4; ++k) {
        int t = s - 3 + k;
        if (t >= 0) {
            int lorig = rev ? (L_ - 1 - t) : t;
            acc += cw[d * 4 + k] * bf2f(xz[((size_t)b * L_ + lorig) * 1536 + d]);
        }
    }
    xc[i] = f2bf(silu_f(acc));
}

// dbl(m, 56) = xc(m, 768) @ xpW(56,768)^T ; one block per token
__global__ __launch_bounds__(256) void xproj_kernel(
    const u16* __restrict__ xc, const float* __restrict__ xpW, float* __restrict__ dbl)
{
    int m = blockIdx.x;
    __shared__ float xs[DI_];
    int tid = threadIdx.x;
    for (int i = tid; i < DI_; i += 256) xs[i] = bf2f(xc[(size_t)m * DI_ + i]);
    __syncthreads();
    int wave = tid >> 6, lane = tid & 63;
    for (int e = wave; e < 56; e += 4) {
        const float* wr = xpW + (size_t)e * DI_;
        float s = 0.f;
#pragma unroll
        for (int i = 0; i < DI_ / 64; ++i) s += xs[lane + 64 * i] * wr[lane + 64 * i];
        s += __shfl_xor(s, 32); s += __shfl_xor(s, 16); s += __shfl_xor(s, 8);
        s += __shfl_xor(s, 4);  s += __shfl_xor(s, 2);  s += __shfl_xor(s, 1);
        if (lane == 0) dbl[(size_t)m * 56 + e] = s;
    }
}

// delta(m,768) = softplus(dt(m,24) @ dtW(768,24)^T + dtb)
__global__ __launch_bounds__(256) void dtproj_kernel(
    const float* __restrict__ dbl, const float* __restrict__ dtW,
    const float* __restrict__ dtb, u16* __restrict__ delta)
{
    int m = blockIdx.x;
    __shared__ float dts[DTR_];
    int tid = threadIdx.x;
    if (tid < DTR_) dts[tid] = dbl[(size_t)m * 56 + tid];
    __syncthreads();
    for (int d = tid; d < DI_; d += 256) {
        const float* wr = dtW + (size_t)d * DTR_;
        float s = dtb[d];
#pragma unroll
        for (int r = 0; r < DTR_; ++r) s += dts[r] * wr[r];
        delta[(size_t)m * DI_ + d] = f2bf(softplus_f(s));
    }
}

// selective scan: lane = (d within 4, n within 16); wave covers 4 channels
__global__ __launch_bounds__(256) void scan_kernel(
    const u16* __restrict__ xc, const float* __restrict__ dbl,
    const u16* __restrict__ delta, const u16* __restrict__ xz,
    const float* __restrict__ Alog, const float* __restrict__ Dp,
    u16* __restrict__ ysum, int rev, int accum)
{
    int tid = threadIdx.x;
    int lane = tid & 63;
    int n = lane & 15;
    int dq = lane >> 4;
    int wave = tid >> 6;
    int b = blockIdx.x / 48;
    int dblk = blockIdx.x % 48;
    int d = dblk * 16 + wave * 4 + dq;

    float Aval = -__expf(Alog[d * DS_ + n]);
    float Dval = Dp[d];
    float h = 0.f;
    size_t mb = (size_t)b * L_;

    float dl = bf2f(delta[(mb + 0) * DI_ + d]);
    float xv = bf2f(xc[(mb + 0) * DI_ + d]);
    float Bv = dbl[(mb + 0) * 56 + 24 + n];
    float Cv = dbl[(mb + 0) * 56 + 40 + n];

    for (int t = 0; t < L_; ++t) {
        float dl_n = 0.f, xv_n = 0.f, Bv_n = 0.f, Cv_n = 0.f;
        if (t + 1 < L_) {
            size_t m = mb + t + 1;
            dl_n = bf2f(delta[m * DI_ + d]);
            xv_n = bf2f(xc[m * DI_ + d]);
            Bv_n = dbl[m * 56 + 24 + n];
            Cv_n = dbl[m * 56 + 40 + n];
        }
        float dA = __expf(dl * Aval);
        h = dA * h + dl * Bv * xv;
        float yp = h * Cv;
        yp += __shfl_xor(yp, 8); yp += __shfl_xor(yp, 4);
        yp += __shfl_xor(yp, 2); yp += __shfl_xor(yp, 1);
        if (n == 0) {
            int lorig = rev ? (L_ - 1 - t) : t;
            float y = yp + xv * Dval;
            float zv = bf2f(xz[(mb + lorig) * 1536 + 768 + d]);
            y *= silu_f(zv);
            u16* yptr = &ysum[(mb + lorig) * DI_ + d];
            *yptr = f2bf(accum ? (bf2f(*yptr) + y) : y);
        }
        dl = dl_n; xv = xv_n; Bv = Bv_n; Cv = Cv_n;
    }
}

// final: residual+hidden, rmsnorm, permute+slice, store bf16 or f32 per flag
__global__ __launch_bounds__(128) void final_kernel(
    const float* __restrict__ hidden, const float* __restrict__ resid,
    const float* __restrict__ w, void* __restrict__ out,
    const int* __restrict__ flag)
{
    int blk = blockIdx.x;
    int b = blk / 446, tok = blk % 446;
    int lorig; size_t dst;
    if (tok == 0)      { lorig = 247; dst = (size_t)b * D_; }
    else if (tok <= 14){ int j = tok - 1; lorig = 49 + j; dst = 6144 + ((size_t)b * 14 + j) * D_; }
    else               { int v = tok - 15; lorig = (v < 184) ? (63 + v) : (64 + v);
                         dst = 92160 + ((size_t)b * 431 + v) * D_; }
    size_t base = ((size_t)b * L_ + lorig) * D_;
    int tid = threadIdx.x;
    float v3[3]; float ss = 0.f;
#pragma unroll
    for (int i = 0; i < 3; ++i) {
        int c = tid + i * 128;
        float r = hidden[base + c] + resid[base + c];
        v3[i] = r; ss += r * r;
    }
    ss += __shfl_xor(ss, 32); ss += __shfl_xor(ss, 16); ss += __shfl_xor(ss, 8);
    ss += __shfl_xor(ss, 4);  ss += __shfl_xor(ss, 2);  ss += __shfl_xor(ss, 1);
    __shared__ float sred[2];
    if ((tid & 63) == 0) sred[tid >> 6] = ss;
    __syncthreads();
    float scale = rsqrtf((sred[0] + sred[1]) * (1.f / D_) + 1e-5f);
    int isbf = *flag;
#pragma unroll
    for (int i = 0; i < 3; ++i) {
        int c = tid + i * 128;
        float val = v3[i] * scale * w[c];
        if (isbf) ((u16*)out)[dst + c] = f2bf(val);
        else      ((float*)out)[dst + c] = val;
    }
}

extern "C" void kernel_launch(void* const* d_in, const int* in_sizes, int n_in,
                              void* d_out, int out_size, void* d_ws, size_t ws_size,
                              hipStream_t stream) {
    // ---- workspace layout
    char* wsb = (char*)d_ws;
    int* flag = (int*)wsb;  wsb += 16;

    // canonical f32 copies of all float tensors
    const int cn[14] = {3035136, 384, 190080, 2359296, 24576, 6144, 344064,
                        147456, 6144, 98304, 6144, 1179648, 1536, 384};
    const int raw_idx[14] = {0, 2, 3, 4, 5, 6, 7, 8, 9, 10, 11, 12, 13, 14};
    float* canon[14];
    for (int i = 0; i < 14; ++i) { canon[i] = (float*)wsb; wsb += (size_t)cn[i] * 4; }
    const float* cjv  = canon[0];
    const float* cls  = canon[1];
    const float* pos  = canon[2];
    const float* inW  = canon[3];
    const float* cW   = canon[4];
    const float* cB   = canon[5];
    const float* xpW  = canon[6];
    const float* dtW  = canon[7];
    const float* dtB  = canon[8];
    const float* Alog = canon[9];
    const float* Dsk  = canon[10];
    const float* outW = canon[11];
    const float* nw   = canon[12];
    const float* fnw  = canon[13];

    const int M = B_ * L_;  // 7920 tokens
    float* hidden = (float*)wsb;  wsb += (size_t)M * D_ * 4;
    float* resid  = (float*)wsb;  wsb += (size_t)M * D_ * 4;
    float* dbl    = (float*)wsb;  wsb += (size_t)M * 56 * 4;
    u16*   xz     = (u16*)wsb;    wsb += (size_t)M * 1536 * 2;
    u16*   xc     = (u16*)wsb;    wsb += (size_t)M * DI_ * 2;
    u16*   delta  = (u16*)wsb;    wsb += (size_t)M * DI_ * 2;
    u16*   ysum   = (u16*)wsb;    wsb += (size_t)M * DI_ * 2;

    // ---- detect dtype, convert everything to canonical f32
    detect_kernel<<<1, 256, 0, stream>>>((const u16*)d_in[10], flag);
    for (int i = 0; i < 14; ++i)
        cvt_kernel<<<(cn[i] + 255) / 256, 256, 0, stream>>>(
            d_in[raw_idx[i]], canon[i], cn[i], flag);

    build_hidden_kernel<<<(M * D_) / 256, 256, 0, stream>>>(cjv, cls, pos, hidden);

    for (int l = 0; l < 4; ++l) {
        resnorm_kernel<<<M, 128, 0, stream>>>(hidden, resid, nw + (size_t)l * D_, l == 0);
        gemm_aw_t<1, 0><<<dim3((M + BM - 1) / BM, 1536 / BN), 256, 0, stream>>>(
            hidden, inW + (size_t)l * 1536 * D_, xz, M, 1536, D_, 1536, 1.f);
        for (int dir = 0; dir < 2; ++dir) {
            int ld = l * 2 + dir;
            conv_silu_kernel<<<(M * DI_) / 256, 256, 0, stream>>>(
                xz, cW + (size_t)ld * DI_ * 4, cB + (size_t)ld * DI_, xc, dir);
            xproj_kernel<<<M, 256, 0, stream>>>(xc, xpW + (size_t)ld * 56 * DI_, dbl);
            dtproj_kernel<<<M, 256, 0, stream>>>(
                dbl, dtW + (size_t)ld * DI_ * DTR_, dtB + (size_t)ld * DI_, delta);
            scan_kernel<<<B_ * 48, 256, 0, stream>>>(
                xc, dbl, delta, xz, Alog + (size_t)ld * DI_ * DS_, Dsk + (size_t)ld * DI_,
                ysum, dir, dir);
        }
        gemm_aw_t<0, 1><<<dim3((M + BM - 1) / BM, D_ / BN), 256, 0, stream>>>(
            ysum, outW + (size_t)l * D_ * DI_, hidden, M, D_, DI_, D_, 0.5f);
    }

    final_kernel<<<B_ * 446, 128, 0, stream>>>(hidden, resid, fnw, d_out, flag);
}

// Round 4
// 4650.154 us; speedup vs baseline: 1.1976x; 1.1976x over previous
//
#include <hip/hip_runtime.h>

typedef unsigned short u16;

#define B_   16
#define L_   495
#define D_   384
#define DI_  768
#define DS_  16
#define DTR_ 24

__device__ __forceinline__ float bf2f(u16 u) {
    return __uint_as_float(((unsigned)u) << 16);
}
__device__ __forceinline__ u16 f2bf(float f) {
    unsigned u = __float_as_uint(f);
    unsigned r = 0x7fffu + ((u >> 16) & 1u);
    return (u16)((u + r) >> 16);
}
__device__ __forceinline__ float silu_f(float x) {
    return x / (1.f + __expf(-x));
}
__device__ __forceinline__ float softplus_f(float x) {
    if (x > 15.f) return x;
    return log1pf(__expf(x));
}

// ---- dtype detector: A_log values are in [0, 2.78]. flag=1 -> bf16, 0 -> f32.
__global__ __launch_bounds__(256) void detect_kernel(
    const u16* __restrict__ alog_raw, int* __restrict__ flag)
{
    __shared__ int s_bad;
    if (threadIdx.x == 0) s_bad = 0;
    __syncthreads();
    int bad = 0;
    for (int i = threadIdx.x; i < 98304; i += 256) {
        float v = bf2f(alog_raw[i]);
        if (!(v >= -1e-3f && v <= 2.8f)) bad = 1;
    }
    if (bad) atomicAdd(&s_bad, 1);
    __syncthreads();
    if (threadIdx.x == 0) *flag = (s_bad == 0) ? 1 : 0;
}

// ---- convert raw tensor (bf16 or f32 per flag) to canonical f32
__global__ __launch_bounds__(256) void cvt_kernel(
    const void* __restrict__ src, float* __restrict__ dst, int n,
    const int* __restrict__ flag)
{
    int i = blockIdx.x * 256 + threadIdx.x;
    if (i >= n) return;
    if (*flag) dst[i] = bf2f(((const u16*)src)[i]);
    else       dst[i] = ((const float*)src)[i];
}

// hidden[b,l,c] = concat(cjv[:247], cls, cjv[247:]) + pos_embed
__global__ __launch_bounds__(256) void build_hidden_kernel(
    const float* __restrict__ cjv, const float* __restrict__ cls,
    const float* __restrict__ pos, float* __restrict__ hidden)
{
    int i = blockIdx.x * 256 + threadIdx.x;
    int c = i % D_;
    int l = (i / D_) % L_;
    int b = i / (D_ * L_);
    float v;
    if (l < 247)       v = cjv[((size_t)b * 494 + l) * D_ + c];
    else if (l == 247) v = cls[c];
    else               v = cjv[((size_t)b * 494 + (l - 1)) * D_ + c];
    hidden[i] = v + pos[(size_t)l * D_ + c];
}

// resid = hidden (+ resid); hidden <- rmsnorm(resid)*w   (in-place norm)
__global__ __launch_bounds__(128) void resnorm_kernel(
    float* __restrict__ hidden, float* __restrict__ resid,
    const float* __restrict__ w, int first)
{
    int m = blockIdx.x, tid = threadIdx.x;
    size_t base = (size_t)m * D_;
    float v[3]; float ss = 0.f;
#pragma unroll
    for (int i = 0; i < 3; ++i) {
        int c = tid + i * 128;
        float r = hidden[base + c];
        if (!first) r += resid[base + c];
        resid[base + c] = r;
        v[i] = r; ss += r * r;
    }
    ss += __shfl_xor(ss, 32); ss += __shfl_xor(ss, 16); ss += __shfl_xor(ss, 8);
    ss += __shfl_xor(ss, 4);  ss += __shfl_xor(ss, 2);  ss += __shfl_xor(ss, 1);
    __shared__ float sred[2];
    if ((tid & 63) == 0) sred[tid >> 6] = ss;
    __syncthreads();
    float scale = rsqrtf((sred[0] + sred[1]) * (1.f / D_) + 1e-5f);
#pragma unroll
    for (int i = 0; i < 3; ++i) {
        int c = tid + i * 128;
        hidden[base + c] = v[i] * scale * w[c];
    }
}

// C(M,N) = alpha * A(M,K) @ W(N,K)^T   (A f32 or bf16; W f32; C f32 or bf16)
#define BM 64
#define BN 64
#define BKg 16
template<int AF32, int CF32>
__global__ __launch_bounds__(256) void gemm_aw_t(
    const void* __restrict__ Av, const float* __restrict__ W, void* __restrict__ Cv,
    int M, int N, int K, int ldc, float alpha)
{
    __shared__ float As[BKg][BM + 1];
    __shared__ float Ws[BKg][BN + 1];
    int m0 = blockIdx.x * BM, n0 = blockIdx.y * BN;
    int tid = threadIdx.x;
    int ty = tid >> 4, tx = tid & 15;
    int lr = tid >> 2, lk = (tid & 3) << 2;
    float acc[4][4] = {};
    for (int k0 = 0; k0 < K; k0 += BKg) {
        int am = m0 + lr;
        float a0 = 0.f, a1 = 0.f, a2 = 0.f, a3 = 0.f;
        if (am < M) {
            if (AF32) {
                float4 av = *reinterpret_cast<const float4*>(
                    (const float*)Av + (size_t)am * K + k0 + lk);
                a0 = av.x; a1 = av.y; a2 = av.z; a3 = av.w;
            } else {
                ushort4 av = *reinterpret_cast<const ushort4*>(
                    (const u16*)Av + (size_t)am * K + k0 + lk);
                a0 = bf2f(av.x); a1 = bf2f(av.y); a2 = bf2f(av.z); a3 = bf2f(av.w);
            }
        }
        As[lk][lr] = a0; As[lk + 1][lr] = a1; As[lk + 2][lr] = a2; As[lk + 3][lr] = a3;
        float4 wv = *reinterpret_cast<const float4*>(W + (size_t)(n0 + lr) * K + k0 + lk);
        Ws[lk][lr] = wv.x; Ws[lk + 1][lr] = wv.y;
        Ws[lk + 2][lr] = wv.z; Ws[lk + 3][lr] = wv.w;
        __syncthreads();
#pragma unroll
        for (int kk = 0; kk < BKg; ++kk) {
            float b0 = As[kk][ty * 4], b1 = As[kk][ty * 4 + 1];
            float b2 = As[kk][ty * 4 + 2], b3 = As[kk][ty * 4 + 3];
            float c0 = Ws[kk][tx * 4], c1 = Ws[kk][tx * 4 + 1];
            float c2 = Ws[kk][tx * 4 + 2], c3 = Ws[kk][tx * 4 + 3];
            acc[0][0] += b0 * c0; acc[0][1] += b0 * c1; acc[0][2] += b0 * c2; acc[0][3] += b0 * c3;
            acc[1][0] += b1 * c0; acc[1][1] += b1 * c1; acc[1][2] += b1 * c2; acc[1][3] += b1 * c3;
            acc[2][0] += b2 * c0; acc[2][1] += b2 * c1; acc[2][2] += b2 * c2; acc[2][3] += b2 * c3;
            acc[3][0] += b3 * c0; acc[3][1] += b3 * c1; acc[3][2] += b3 * c2; acc[3][3] += b3 * c3;
        }
        __syncthreads();
    }
#pragma unroll
    for (int i = 0; i < 4; ++i) {
        int m = m0 + ty * 4 + i;
        if (m >= M) continue;
#pragma unroll
        for (int j = 0; j < 4; ++j) {
            float val = alpha * acc[i][j];
            if (CF32) ((float*)Cv)[(size_t)m * ldc + n0 + tx * 4 + j] = val;
            else      ((u16*)Cv)[(size_t)m * ldc + n0 + tx * 4 + j] = f2bf(val);
        }
    }
}

// causal depthwise conv (K=4) + bias + silu, in scan order; xin = xz[:, :768]
__global__ __launch_bounds__(256) void conv_silu_kernel(
    const u16* __restrict__ xz, const float* __restrict__ cw,
    const float* __restrict__ cb, u16* __restrict__ xc, int rev)
{
    int i = blockIdx.x * 256 + threadIdx.x;
    int d = i % DI_;
    int s = (i / DI_) % L_;
    int b = i / (DI_ * L_);
    float acc = cb[d];
#pragma unroll
    for (int k = 0; k < 4; ++k) {
        int t = s - 3 + k;
        if (t >= 0) {
            int lorig = rev ? (L_ - 1 - t) : t;
            acc += cw[d * 4 + k] * bf2f(xz[((size_t)b * L_ + lorig) * 1536 + d]);
        }
    }
    xc[i] = f2bf(silu_f(acc));
}

// dbl(m, 56) = xc(m, 768) @ xpW(56,768)^T ; one block per token
__global__ __launch_bounds__(256) void xproj_kernel(
    const u16* __restrict__ xc, const float* __restrict__ xpW, float* __restrict__ dbl)
{
    int m = blockIdx.x;
    __shared__ float xs[DI_];
    int tid = threadIdx.x;
    for (int i = tid; i < DI_; i += 256) xs[i] = bf2f(xc[(size_t)m * DI_ + i]);
    __syncthreads();
    int wave = tid >> 6, lane = tid & 63;
    for (int e = wave; e < 56; e += 4) {
        const float* wr = xpW + (size_t)e * DI_;
        float s = 0.f;
#pragma unroll
        for (int i = 0; i < DI_ / 64; ++i) s += xs[lane + 64 * i] * wr[lane + 64 * i];
        s += __shfl_xor(s, 32); s += __shfl_xor(s, 16); s += __shfl_xor(s, 8);
        s += __shfl_xor(s, 4);  s += __shfl_xor(s, 2);  s += __shfl_xor(s, 1);
        if (lane == 0) dbl[(size_t)m * 56 + e] = s;
    }
}

// delta(m,768) = softplus(dt(m,24) @ dtW(768,24)^T + dtb)
__global__ __launch_bounds__(256) void dtproj_kernel(
    const float* __restrict__ dbl, const float* __restrict__ dtW,
    const float* __restrict__ dtb, u16* __restrict__ delta)
{
    int m = blockIdx.x;
    __shared__ float dts[DTR_];
    int tid = threadIdx.x;
    if (tid < DTR_) dts[tid] = dbl[(size_t)m * 56 + tid];
    __syncthreads();
    for (int d = tid; d < DI_; d += 256) {
        const float* wr = dtW + (size_t)d * DTR_;
        float s = dtb[d];
#pragma unroll
        for (int r = 0; r < DTR_; ++r) s += dts[r] * wr[r];
        delta[(size_t)m * DI_ + d] = f2bf(softplus_f(s));
    }
}

// selective scan v2: one lane per (b,d) channel, 16 states in registers.
// grid = B_ * 12 blocks of 64 threads; lane d = (blk%12)*64 + tid.
__global__ __launch_bounds__(64) void scan_v2_kernel(
    const u16* __restrict__ xc, const float* __restrict__ dbl,
    const u16* __restrict__ delta, const u16* __restrict__ xz,
    const float* __restrict__ Alog, const float* __restrict__ Dp,
    u16* __restrict__ ysum, int rev, int accum)
{
    int lane = threadIdx.x;
    int b = blockIdx.x / 12;
    int d = (blockIdx.x % 12) * 64 + lane;
    size_t mb = (size_t)b * L_;

    float A[16];
    {
        const float4* ap = reinterpret_cast<const float4*>(Alog + (size_t)d * 16);
#pragma unroll
        for (int i = 0; i < 4; ++i) {
            float4 a4 = ap[i];
            A[4 * i + 0] = -__expf(a4.x); A[4 * i + 1] = -__expf(a4.y);
            A[4 * i + 2] = -__expf(a4.z); A[4 * i + 3] = -__expf(a4.w);
        }
    }
    float Dval = Dp[d];
    float h[16];
#pragma unroll
    for (int i = 0; i < 16; ++i) h[i] = 0.f;

    // prefetch t = 0
    float dl = bf2f(delta[mb * DI_ + d]);
    float xv = bf2f(xc[mb * DI_ + d]);
    int lo0 = rev ? (L_ - 1) : 0;
    float zv = bf2f(xz[(mb + lo0) * 1536 + 768 + d]);
    float yold = accum ? bf2f(ysum[(mb + lo0) * DI_ + d]) : 0.f;
    float4 Bv[4], Cv[4];
    {
        const float4* p = reinterpret_cast<const float4*>(dbl + mb * 56 + 24);
#pragma unroll
        for (int i = 0; i < 4; ++i) { Bv[i] = p[i]; Cv[i] = p[4 + i]; }
    }

    for (int t = 0; t < L_; ++t) {
        // prefetch t+1
        float dl_n = 0.f, xv_n = 0.f, zv_n = 0.f, yold_n = 0.f;
        float4 Bn[4], Cn[4];
#pragma unroll
        for (int i = 0; i < 4; ++i) {
            Bn[i] = make_float4(0.f, 0.f, 0.f, 0.f);
            Cn[i] = make_float4(0.f, 0.f, 0.f, 0.f);
        }
        if (t + 1 < L_) {
            size_t m = mb + t + 1;
            dl_n = bf2f(delta[m * DI_ + d]);
            xv_n = bf2f(xc[m * DI_ + d]);
            int lo = rev ? (L_ - 2 - t) : (t + 1);
            zv_n = bf2f(xz[(mb + lo) * 1536 + 768 + d]);
            if (accum) yold_n = bf2f(ysum[(mb + lo) * DI_ + d]);
            const float4* p = reinterpret_cast<const float4*>(dbl + m * 56 + 24);
#pragma unroll
            for (int i = 0; i < 4; ++i) { Bn[i] = p[i]; Cn[i] = p[4 + i]; }
        }

        // compute t
        float dlxv = dl * xv;
        float a0 = 0.f, a1 = 0.f, a2 = 0.f, a3 = 0.f;
#pragma unroll
        for (int i = 0; i < 4; ++i) {
            float bx = Bv[i].x, by = Bv[i].y, bz = Bv[i].z, bw = Bv[i].w;
            float cx = Cv[i].x, cy = Cv[i].y, cz = Cv[i].z, cw = Cv[i].w;
            float e0 = __expf(dl * A[4 * i + 0]);
            float e1 = __expf(dl * A[4 * i + 1]);
            float e2 = __expf(dl * A[4 * i + 2]);
            float e3 = __expf(dl * A[4 * i + 3]);
            h[4 * i + 0] = e0 * h[4 * i + 0] + dlxv * bx;
            h[4 * i + 1] = e1 * h[4 * i + 1] + dlxv * by;
            h[4 * i + 2] = e2 * h[4 * i + 2] + dlxv * bz;
            h[4 * i + 3] = e3 * h[4 * i + 3] + dlxv * bw;
            a0 += h[4 * i + 0] * cx;
            a1 += h[4 * i + 1] * cy;
            a2 += h[4 * i + 2] * cz;
            a3 += h[4 * i + 3] * cw;
        }
        float y = (a0 + a1) + (a2 + a3) + xv * Dval;
        y *= silu_f(zv);
        int lorig = rev ? (L_ - 1 - t) : t;
        ysum[(mb + lorig) * DI_ + d] = f2bf(accum ? (yold + y) : y);

        dl = dl_n; xv = xv_n; zv = zv_n; yold = yold_n;
#pragma unroll
        for (int i = 0; i < 4; ++i) { Bv[i] = Bn[i]; Cv[i] = Cn[i]; }
    }
}

// final: residual+hidden, rmsnorm, permute+slice, store bf16 or f32 per flag
__global__ __launch_bounds__(128) void final_kernel(
    const float* __restrict__ hidden, const float* __restrict__ resid,
    const float* __restrict__ w, void* __restrict__ out,
    const int* __restrict__ flag)
{
    int blk = blockIdx.x;
    int b = blk / 446, tok = blk % 446;
    int lorig; size_t dst;
    if (tok == 0)      { lorig = 247; dst = (size_t)b * D_; }
    else if (tok <= 14){ int j = tok - 1; lorig = 49 + j; dst = 6144 + ((size_t)b * 14 + j) * D_; }
    else               { int v = tok - 15; lorig = (v < 184) ? (63 + v) : (64 + v);
                         dst = 92160 + ((size_t)b * 431 + v) * D_; }
    size_t base = ((size_t)b * L_ + lorig) * D_;
    int tid = threadIdx.x;
    float v3[3]; float ss = 0.f;
#pragma unroll
    for (int i = 0; i < 3; ++i) {
        int c = tid + i * 128;
        float r = hidden[base + c] + resid[base + c];
        v3[i] = r; ss += r * r;
    }
    ss += __shfl_xor(ss, 32); ss += __shfl_xor(ss, 16); ss += __shfl_xor(ss, 8);
    ss += __shfl_xor(ss, 4);  ss += __shfl_xor(ss, 2);  ss += __shfl_xor(ss, 1);
    __shared__ float sred[2];
    if ((tid & 63) == 0) sred[tid >> 6] = ss;
    __syncthreads();
    float scale = rsqrtf((sred[0] + sred[1]) * (1.f / D_) + 1e-5f);
    int isbf = *flag;
#pragma unroll
    for (int i = 0; i < 3; ++i) {
        int c = tid + i * 128;
        float val = v3[i] * scale * w[c];
        if (isbf) ((u16*)out)[dst + c] = f2bf(val);
        else      ((float*)out)[dst + c] = val;
    }
}

extern "C" void kernel_launch(void* const* d_in, const int* in_sizes, int n_in,
                              void* d_out, int out_size, void* d_ws, size_t ws_size,
                              hipStream_t stream) {
    // ---- workspace layout
    char* wsb = (char*)d_ws;
    int* flag = (int*)wsb;  wsb += 16;

    const int cn[14] = {3035136, 384, 190080, 2359296, 24576, 6144, 344064,
                        147456, 6144, 98304, 6144, 1179648, 1536, 384};
    const int raw_idx[14] = {0, 2, 3, 4, 5, 6, 7, 8, 9, 10, 11, 12, 13, 14};
    float* canon[14];
    for (int i = 0; i < 14; ++i) { canon[i] = (float*)wsb; wsb += (size_t)cn[i] * 4; }
    const float* cjv  = canon[0];
    const float* cls  = canon[1];
    const float* pos  = canon[2];
    const float* inW  = canon[3];
    const float* cW   = canon[4];
    const float* cB   = canon[5];
    const float* xpW  = canon[6];
    const float* dtW  = canon[7];
    const float* dtB  = canon[8];
    const float* Alog = canon[9];
    const float* Dsk  = canon[10];
    const float* outW = canon[11];
    const float* nw   = canon[12];
    const float* fnw  = canon[13];

    const int M = B_ * L_;  // 7920 tokens
    float* hidden = (float*)wsb;  wsb += (size_t)M * D_ * 4;
    float* resid  = (float*)wsb;  wsb += (size_t)M * D_ * 4;
    float* dbl    = (float*)wsb;  wsb += (size_t)M * 56 * 4;
    u16*   xz     = (u16*)wsb;    wsb += (size_t)M * 1536 * 2;
    u16*   xc     = (u16*)wsb;    wsb += (size_t)M * DI_ * 2;
    u16*   delta  = (u16*)wsb;    wsb += (size_t)M * DI_ * 2;
    u16*   ysum   = (u16*)wsb;    wsb += (size_t)M * DI_ * 2;

    detect_kernel<<<1, 256, 0, stream>>>((const u16*)d_in[10], flag);
    for (int i = 0; i < 14; ++i)
        cvt_kernel<<<(cn[i] + 255) / 256, 256, 0, stream>>>(
            d_in[raw_idx[i]], canon[i], cn[i], flag);

    build_hidden_kernel<<<(M * D_) / 256, 256, 0, stream>>>(cjv, cls, pos, hidden);

    for (int l = 0; l < 4; ++l) {
        resnorm_kernel<<<M, 128, 0, stream>>>(hidden, resid, nw + (size_t)l * D_, l == 0);
        gemm_aw_t<1, 0><<<dim3((M + BM - 1) / BM, 1536 / BN), 256, 0, stream>>>(
            hidden, inW + (size_t)l * 1536 * D_, xz, M, 1536, D_, 1536, 1.f);
        for (int dir = 0; dir < 2; ++dir) {
            int ld = l * 2 + dir;
            conv_silu_kernel<<<(M * DI_) / 256, 256, 0, stream>>>(
                xz, cW + (size_t)ld * DI_ * 4, cB + (size_t)ld * DI_, xc, dir);
            xproj_kernel<<<M, 256, 0, stream>>>(xc, xpW + (size_t)ld * 56 * DI_, dbl);
            dtproj_kernel<<<M, 256, 0, stream>>>(
                dbl, dtW + (size_t)ld * DI_ * DTR_, dtB + (size_t)ld * DI_, delta);
            scan_v2_kernel<<<B_ * 12, 64, 0, stream>>>(
                xc, dbl, delta, xz, Alog + (size_t)ld * DI_ * DS_, Dsk + (size_t)ld * DI_,
                ysum, dir, dir);
        }
        gemm_aw_t<0, 1><<<dim3((M + BM - 1) / BM, D_ / BN), 256, 0, stream>>>(
            ysum, outW + (size_t)l * D_ * DI_, hidden, M, D_, DI_, D_, 0.5f);
    }

    final_kernel<<<B_ * 446, 128, 0, stream>>>(hidden, resid, fnw, d_out, flag);
}